// Round 3
// baseline (214.141 us; speedup 1.0000x reference)
//
#include <hip/hip_runtime.h>

// entmax-1.5 n-section loss, wave-autonomous 3-kernel design (no barriers).
//
// X:(n, c) fp32, here (4096, 32000). Xs = X/2; tau in [mx-1, mx] (Xs units)
// via 9 iters of 4-section search on f(tau) = sum relu(Xs-tau)^2 - 1.
// Only elements with Xs > rowmax_s - 1  <=>  x > rowmax_x - 2 ever matter.
//
// pass1:  one WAVE per 2048-elem chunk. 8xfloat4/lane register-resident, wave
//         max (shuffle only), gather superset {x > wavemax-2} to ws slot via
//         ballot compaction. No LDS, no __syncthreads -> pure streaming.
// search: one wave per row. Exact row max from 16 chunk maxes; filter the
//         superset to the exact candidate set into LDS; 27 dependent passes
//         run from LDS (not L2). Per-row overflow -> full-scan fallback.
// reduce: mean of row losses.

#define NITER 9
#define CHUNK 2048     // elements per pass1 wave
#define VPT4  8        // float4 per lane: 8*4*64 = 2048
#define WCAP  1024     // ws capacity per chunk (expected ~200, worst ~500)
#define RCAP  3072     // filtered per-row LDS capacity (expected ~200-1800)
#define SW    4        // rows (waves) per search block

__device__ __forceinline__ float wave_max_f(float m) {
    #pragma unroll
    for (int off = 32; off > 0; off >>= 1) m = fmaxf(m, __shfl_xor(m, off));
    return m;
}
__device__ __forceinline__ float wave_sum_f(float s) {
    #pragma unroll
    for (int off = 32; off > 0; off >>= 1) s += __shfl_xor(s, off);
    return s;
}

// Correct-but-slow wave-level full-row scan (fallback paths only).
__device__ float row_loss_fullscan(const float* __restrict__ Xr, int c,
                                   int lane, int tg) {
    float m = -3e38f;
    for (int i = lane; i < c; i += 64) m = fmaxf(m, Xr[i]);
    m = wave_max_f(m);
    float lo = 0.5f * m - 1.0f, hi = 0.5f * m;
    for (int it = 0; it < NITER; ++it) {
        const float w  = (hi - lo) * 0.25f;
        const float t1 = lo + w, t2 = lo + 2.0f * w, t3 = lo + 3.0f * w;
        float f1 = 0.f, f2 = 0.f, f3 = 0.f;
        for (int i = lane; i < c; i += 64) {
            const float x = 0.5f * Xr[i];
            float d;
            d = fmaxf(x - t1, 0.f); f1 = fmaf(d, d, f1);
            d = fmaxf(x - t2, 0.f); f2 = fmaf(d, d, f2);
            d = fmaxf(x - t3, 0.f); f3 = fmaf(d, d, f3);
        }
        f1 = wave_sum_f(f1); f2 = wave_sum_f(f2); f3 = wave_sum_f(f3);
        const int cc = (f1 >= 1.f) + (f2 >= 1.f) + (f3 >= 1.f);
        lo += w * (float)cc;
        hi = lo + w;
    }
    const float tau = 0.5f * (lo + hi);
    float S1 = 0.f, SX = 0.f, S3 = 0.f;
    for (int i = lane; i < c; i += 64) {
        const float x = 0.5f * Xr[i];
        const float d = fmaxf(x - tau, 0.f), q = d * d;
        S1 += q; SX = fmaf(q, x, SX); S3 = fmaf(q, d, S3);
    }
    S1 = wave_sum_f(S1); SX = wave_sum_f(SX); S3 = wave_sum_f(S3);
    const float omega = (1.f - S3 / (S1 * sqrtf(S1))) * (4.f / 3.f);
    return omega + 2.f * SX / S1 - Xr[tg];
}

// ---------------------------------------------------------------------------
// pass1: wave-per-chunk streamer + superset gather. No LDS, no barriers.
// ---------------------------------------------------------------------------
__global__ __launch_bounds__(256, 4)
void pass1_kernel(const float* __restrict__ X,
                  float* __restrict__ maxes,
                  int*   __restrict__ counts,
                  float* __restrict__ cand,
                  int c, int cpr, int nchunks) {
    const int wid  = blockIdx.x * 4 + (threadIdx.x >> 6);
    const int lane = threadIdx.x & 63;
    if (wid >= nchunks) return;
    const int r    = wid / cpr;
    const int ch   = wid - r * cpr;
    const int base = ch * CHUNK;
    const int len  = min(CHUNK, c - base);     // >0; multiple of 4 (c%4==0)
    const float* __restrict__ Xc = X + (size_t)r * (size_t)c + base;

    const int len4 = len >> 2;
    float4 v[VPT4];
    #pragma unroll
    for (int k = 0; k < VPT4; ++k) {
        const int i4 = lane + (k << 6);
        if (i4 < len4) v[k] = ((const float4*)Xc)[i4];
        else { v[k].x = v[k].y = v[k].z = v[k].w = -3e38f; }
    }

    float m = -3e38f;
    #pragma unroll
    for (int k = 0; k < VPT4; ++k)
        m = fmaxf(m, fmaxf(fmaxf(v[k].x, v[k].y), fmaxf(v[k].z, v[k].w)));
    m = wave_max_f(m);
    const float t0 = m - 2.0f;                  // raw-x superset threshold

    float* __restrict__ slot = cand + (size_t)wid * WCAP;
    const unsigned long long lt = (((unsigned long long)1) << lane) - 1ull;
    int total = 0;
    #pragma unroll
    for (int k = 0; k < VPT4; ++k) {
        const float e[4] = {v[k].x, v[k].y, v[k].z, v[k].w};
        #pragma unroll
        for (int j = 0; j < 4; ++j) {
            const bool p = e[j] > t0;
            const unsigned long long b = __ballot(p);
            const int pos = total + __popcll(b & lt);
            if (p && pos < WCAP) slot[pos] = e[j];
            total += (int)__popcll(b);
        }
    }
    if (lane == 0) { maxes[wid] = m; counts[wid] = total; }
}

// ---------------------------------------------------------------------------
// search: one wave per row; exact filter into LDS, then LDS-resident search.
// ---------------------------------------------------------------------------
__global__ __launch_bounds__(256, 2)
void search_kernel(const float* __restrict__ X,
                   const int*   __restrict__ target,
                   const float* __restrict__ maxes,
                   const int*   __restrict__ counts,
                   const float* __restrict__ cand,
                   float* __restrict__ row_loss,
                   int n, int c, int cpr) {
    __shared__ float lds[SW][RCAP];
    const int wave = threadIdx.x >> 6;
    const int lane = threadIdx.x & 63;
    const int r    = blockIdx.x * SW + wave;
    if (r >= n) return;
    float* __restrict__ rb = lds[wave];
    const float* __restrict__ Xr = X + (size_t)r * (size_t)c;
    const int tg = target[r];

    // exact row max from chunk maxes (cpr <= 64 guaranteed by launcher)
    float m = (lane < cpr) ? maxes[r * cpr + lane] : -3e38f;
    m = wave_max_f(m);
    const float t0 = m - 2.0f;                  // raw-x exact threshold

    bool ovf = (lane < cpr) ? (counts[r * cpr + lane] > WCAP) : false;
    ovf = __any(ovf);

    int cnt = 0;
    if (!ovf) {
        const unsigned long long lt = (((unsigned long long)1) << lane) - 1ull;
        for (int chn = 0; chn < cpr; ++chn) {
            const int cc = counts[r * cpr + chn];
            const float* __restrict__ sl = cand + (size_t)(r * cpr + chn) * WCAP;
            for (int i0 = 0; i0 < cc; i0 += 64) {     // uniform trip count
                const int  i  = i0 + lane;
                const bool vl = i < cc;
                const float x = vl ? sl[i] : -3e38f;
                const bool p  = vl && (x > t0);
                const unsigned long long b = __ballot(p);
                const int pos = cnt + (int)__popcll(b & lt);
                if (p && pos < RCAP) rb[pos] = 0.5f * x;   // store Xs
                cnt += (int)__popcll(b);
            }
        }
        if (cnt > RCAP) ovf = true;
    }

    float loss;
    if (!ovf) {
        float lo = 0.5f * m - 1.0f, hi = 0.5f * m;
        for (int it = 0; it < NITER; ++it) {
            const float w  = (hi - lo) * 0.25f;
            const float t1 = lo + w, t2 = lo + 2.0f * w, t3 = lo + 3.0f * w;
            float f1 = 0.f, f2 = 0.f, f3 = 0.f;
            for (int i = lane; i < cnt; i += 64) {
                const float x = rb[i];
                float d;
                d = fmaxf(x - t1, 0.f); f1 = fmaf(d, d, f1);
                d = fmaxf(x - t2, 0.f); f2 = fmaf(d, d, f2);
                d = fmaxf(x - t3, 0.f); f3 = fmaf(d, d, f3);
            }
            f1 = wave_sum_f(f1); f2 = wave_sum_f(f2); f3 = wave_sum_f(f3);
            const int cc = (f1 >= 1.f) + (f2 >= 1.f) + (f3 >= 1.f);
            lo += w * (float)cc;
            hi = lo + w;
        }
        const float tau = 0.5f * (lo + hi);
        float S1 = 0.f, SX = 0.f, S3 = 0.f;
        for (int i = lane; i < cnt; i += 64) {
            const float x = rb[i];
            const float d = fmaxf(x - tau, 0.f), q = d * d;
            S1 += q; SX = fmaf(q, x, SX); S3 = fmaf(q, d, S3);
        }
        S1 = wave_sum_f(S1); SX = wave_sum_f(SX); S3 = wave_sum_f(S3);
        const float omega = (1.f - S3 / (S1 * sqrtf(S1))) * (4.f / 3.f);
        loss = omega + 2.f * SX / S1 - Xr[tg];
    } else {
        loss = row_loss_fullscan(Xr, c, lane, tg);
    }
    if (lane == 0) row_loss[r] = loss;
}

// ---------------------------------------------------------------------------
// fallback (ws too small / c%4 != 0 / cpr > 64): wave-per-row full scan
// ---------------------------------------------------------------------------
__global__ __launch_bounds__(256, 4)
void fallback_kernel(const float* __restrict__ X, const int* __restrict__ target,
                     float* __restrict__ row_loss, int n, int c) {
    const int wave = threadIdx.x >> 6;
    const int lane = threadIdx.x & 63;
    const int r = blockIdx.x * 4 + wave;
    if (r >= n) return;
    const float* __restrict__ Xr = X + (size_t)r * (size_t)c;
    const float L = row_loss_fullscan(Xr, c, lane, target[r]);
    if (lane == 0) row_loss[r] = L;
}

// ---------------------------------------------------------------------------
__global__ __launch_bounds__(1024)
void reduce_mean_kernel(const float* __restrict__ vv, float* __restrict__ out, int n) {
    __shared__ float s_red[16];
    float s = 0.f;
    for (int i = threadIdx.x; i < n; i += 1024) s += vv[i];
    s = wave_sum_f(s);
    const int wave = threadIdx.x >> 6;
    const int lane = threadIdx.x & 63;
    if (lane == 0) s_red[wave] = s;
    __syncthreads();
    if (threadIdx.x == 0) {
        float t = 0.f;
        for (int i = 0; i < 16; ++i) t += s_red[i];
        out[0] = t / (float)n;
    }
}

extern "C" void kernel_launch(void* const* d_in, const int* in_sizes, int n_in,
                              void* d_out, int out_size, void* d_ws, size_t ws_size,
                              hipStream_t stream) {
    const float* X      = (const float*)d_in[0];
    const int*   target = (const int*)d_in[1];
    float*       out    = (float*)d_out;

    const int n   = in_sizes[1];
    const int c   = in_sizes[0] / n;
    const int cpr = (c + CHUNK - 1) / CHUNK;    // chunks per row
    const long long nchunks = (long long)n * cpr;

    char* ws = (char*)d_ws;
    size_t off = 0;
    float* row_loss = (float*)(ws + off); off += (((size_t)n * 4) + 255) & ~(size_t)255;
    float* maxes    = (float*)(ws + off); off += (((size_t)nchunks * 4) + 255) & ~(size_t)255;
    int*   counts   = (int*)  (ws + off); off += (((size_t)nchunks * 4) + 255) & ~(size_t)255;
    float* cand     = (float*)(ws + off); off += (size_t)nchunks * WCAP * 4;

    const bool fast = (off <= ws_size) && ((c & 3) == 0) && (cpr <= 64) &&
                      (nchunks < (1ll << 31));

    if (fast) {
        const int p1_blocks = (int)((nchunks + 3) / 4);
        pass1_kernel<<<p1_blocks, 256, 0, stream>>>(X, maxes, counts, cand,
                                                    c, cpr, (int)nchunks);
        search_kernel<<<(n + SW - 1) / SW, 256, 0, stream>>>(X, target, maxes, counts,
                                                             cand, row_loss, n, c, cpr);
    } else {
        fallback_kernel<<<(n + 3) / 4, 256, 0, stream>>>(X, target, row_loss, n, c);
    }
    reduce_mean_kernel<<<1, 1024, 0, stream>>>(row_loss, out, n);
}

// Round 4
// 162.526 us; speedup vs baseline: 1.3176x; 1.3176x over previous
//
#include <hip/hip_runtime.h>

// entmax-1.5 n-section loss, monolithic block-per-row, fixed prefilter.
//
// X:(n=4096, c=32000) fp32, rows ~ N(0,1). Xs = X/2; tau in [mx-1, mx]
// (Xs units) via 9 iters of 4-section search on f(tau)=sum relu(Xs-tau)^2-1.
// Only elements with raw x > rowmax - 2 ever contribute (tau >= mx-1).
//
// Fast path per block (= row), 1024 threads:
//  phase1: each wave streams 2048 elems (2 batches x 4 float4/lane, 16 data
//          VGPRs -> no spill at the 64-VGPR cap), tracks wave max, and
//          ballot-compacts the superset {x > 1.5} into its private LDS
//          segment. Deterministic (no atomics), no barriers in the stream.
//  [1 barrier] exact row max from 16 wave maxes (all threads, uniform).
//  coverage check: needs rowmax >= 3.5 (P(violate) ~ 6e-4/row) else in-block
//          full-rescan fallback; segment overflow (>=16 sigma) also falls back.
//  phase2: exact filter {x > rowmax-2} from segments into one LDS array
//          (prefix over 16 per-wave counts), then wave 0 runs the 9x3
//          threshold search + final sums from LDS. Other waves exit.
// reduce: mean of row losses.

#define NITER 9
#define TGRAW 1.5f      // fixed raw-x prefilter (N(0,1) rows)
#define CAPW  320       // per-wave superset capacity (mean 137, sd 11 -> 16 sigma)
#define EXCAP 3072      // exact candidate capacity (worst-case ~2200)
#define NW    16        // waves per block

__device__ __forceinline__ float wave_max_f(float m) {
    #pragma unroll
    for (int off = 32; off > 0; off >>= 1) m = fmaxf(m, __shfl_xor(m, off));
    return m;
}
__device__ __forceinline__ float wave_sum_f(float s) {
    #pragma unroll
    for (int off = 32; off > 0; off >>= 1) s += __shfl_xor(s, off);
    return s;
}

__global__ __launch_bounds__(1024, 8)
void entmax_loss_kernel(const float* __restrict__ X,
                        const int* __restrict__ target,
                        float* __restrict__ row_loss, int c) {
    const int r    = blockIdx.x;
    const int tid  = threadIdx.x;
    const int w    = tid >> 6;
    const int lane = tid & 63;
    const float* __restrict__ Xr = X + (size_t)r * (size_t)c;

    __shared__ float seg[NW][CAPW];
    __shared__ int   segcnt[NW];
    __shared__ float s_red[NW];
    __shared__ int   s_excnt[NW];
    __shared__ float ex[EXCAP];
    __shared__ float s_r3[3][NW];
    __shared__ int   s_flag;
    __shared__ int   s_tg;
    __shared__ float s_xtg;

    if (tid == 0) {
        s_flag = 0;
        const int tg = target[r];
        s_tg = tg;
        s_xtg = Xr[tg];          // prefetched; overlaps the stream below
    }

    // ---- phase 1: stream 2048 elems/wave, wave max + superset compaction ----
    const int c4 = c >> 2;       // launcher guarantees c%4==0 && c<=32768
    const unsigned long long lt = (1ull << lane) - 1ull;
    float* __restrict__ segw = seg[w];
    float m = -3e38f;
    int   cnt = 0;
    for (int b = 0; b < 2; ++b) {
        float4 v[4];
        #pragma unroll
        for (int k = 0; k < 4; ++k) {
            const int i4 = tid + (b * 4 + k) * 1024;
            if (i4 < c4) v[k] = ((const float4*)Xr)[i4];
            else { v[k].x = v[k].y = v[k].z = v[k].w = -3e38f; }
        }
        #pragma unroll
        for (int k = 0; k < 4; ++k) {
            m = fmaxf(m, fmaxf(fmaxf(v[k].x, v[k].y), fmaxf(v[k].z, v[k].w)));
            const float e[4] = {v[k].x, v[k].y, v[k].z, v[k].w};
            #pragma unroll
            for (int j = 0; j < 4; ++j) {
                const bool p = e[j] > TGRAW;
                const unsigned long long bl = __ballot(p);
                const int pos = cnt + (int)__popcll(bl & lt);
                if (p && pos < CAPW) segw[pos] = e[j];
                cnt += (int)__popcll(bl);
            }
        }
    }
    m = wave_max_f(m);
    if (lane == 0) {
        s_red[w] = m;
        segcnt[w] = cnt;
        if (cnt > CAPW) s_flag = 1;   // benign race: all writers store 1
    }
    __syncthreads();

    float rm = s_red[0];
    #pragma unroll
    for (int i = 1; i < NW; ++i) rm = fmaxf(rm, s_red[i]);
    const bool fb = (s_flag != 0) || (rm < TGRAW + 2.0f);

    if (!fb) {
        // ---- phase 2a: count exact keepers (x > rm-2) per wave segment ----
        const float thr = rm - 2.0f;
        const int sc = segcnt[w];
        int ec = 0;
        for (int i0 = 0; i0 < sc; i0 += 64) {
            const int i = i0 + lane;
            const bool p = (i < sc) && (segw[i] > thr);
            ec += (int)__popcll(__ballot(p));
        }
        if (lane == 0) s_excnt[w] = ec;
        __syncthreads();

        int off = 0, total = 0;
        #pragma unroll
        for (int u = 0; u < NW; ++u) {
            const int e = s_excnt[u];
            if (u < w) off += e;
            total += e;
        }
        if (total <= EXCAP) {          // uniform branch
            // ---- phase 2b: compact exact set (store Xs = x/2) ----
            int pos = off;
            for (int i0 = 0; i0 < sc; i0 += 64) {
                const int i = i0 + lane;
                const bool p = (i < sc) && (segw[i] > thr);
                const unsigned long long bl = __ballot(p);
                if (p) ex[pos + (int)__popcll(bl & lt)] = 0.5f * segw[i];
                pos += (int)__popcll(bl);
            }
            __syncthreads();
            // ---- phase 2c: wave 0 searches from LDS; others exit ----
            if (w == 0) {
                float lo = 0.5f * rm - 1.0f, hi = 0.5f * rm;
                for (int it = 0; it < NITER; ++it) {
                    const float w4 = (hi - lo) * 0.25f;
                    const float t1 = lo + w4, t2 = lo + 2.f * w4, t3 = lo + 3.f * w4;
                    float f1 = 0.f, f2 = 0.f, f3 = 0.f;
                    for (int i = lane; i < total; i += 64) {
                        const float x = ex[i];
                        float d;
                        d = fmaxf(x - t1, 0.f); f1 = fmaf(d, d, f1);
                        d = fmaxf(x - t2, 0.f); f2 = fmaf(d, d, f2);
                        d = fmaxf(x - t3, 0.f); f3 = fmaf(d, d, f3);
                    }
                    f1 = wave_sum_f(f1); f2 = wave_sum_f(f2); f3 = wave_sum_f(f3);
                    const int cc = (f1 >= 1.f) + (f2 >= 1.f) + (f3 >= 1.f);
                    lo += w4 * (float)cc;
                    hi = lo + w4;
                }
                const float tau = 0.5f * (lo + hi);
                float S1 = 0.f, SX = 0.f, S3 = 0.f;
                for (int i = lane; i < total; i += 64) {
                    const float x = ex[i];
                    const float d = fmaxf(x - tau, 0.f), q = d * d;
                    S1 += q; SX = fmaf(q, x, SX); S3 = fmaf(q, d, S3);
                }
                S1 = wave_sum_f(S1); SX = wave_sum_f(SX); S3 = wave_sum_f(S3);
                if (lane == 0) {
                    const float omega = (1.f - S3 / (S1 * sqrtf(S1))) * (4.f / 3.f);
                    row_loss[r] = omega + 2.f * SX / S1 - s_xtg;
                }
            }
            return;
        }
        // total > EXCAP (uniform): fall through to full-rescan fallback
    }

    // ---- fallback: full multi-wave re-scan from global (rare) ----
    {
        float lo = 0.5f * rm - 1.0f, hi = 0.5f * rm;   // rm exact even here
        for (int it = 0; it < NITER; ++it) {
            const float w4 = (hi - lo) * 0.25f;
            const float t1 = lo + w4, t2 = lo + 2.f * w4, t3 = lo + 3.f * w4;
            float f1 = 0.f, f2 = 0.f, f3 = 0.f;
            for (int i = tid; i < c; i += 1024) {
                const float x = 0.5f * Xr[i];
                float d;
                d = fmaxf(x - t1, 0.f); f1 = fmaf(d, d, f1);
                d = fmaxf(x - t2, 0.f); f2 = fmaf(d, d, f2);
                d = fmaxf(x - t3, 0.f); f3 = fmaf(d, d, f3);
            }
            f1 = wave_sum_f(f1); f2 = wave_sum_f(f2); f3 = wave_sum_f(f3);
            __syncthreads();                       // protect s_r3 reuse
            if (lane == 0) { s_r3[0][w] = f1; s_r3[1][w] = f2; s_r3[2][w] = f3; }
            __syncthreads();
            float a = 0.f, bb = 0.f, g = 0.f;
            #pragma unroll
            for (int u = 0; u < NW; ++u) { a += s_r3[0][u]; bb += s_r3[1][u]; g += s_r3[2][u]; }
            const int cc = (a >= 1.f) + (bb >= 1.f) + (g >= 1.f);
            lo += w4 * (float)cc;
            hi = lo + w4;
        }
        const float tau = 0.5f * (lo + hi);
        float S1 = 0.f, SX = 0.f, S3 = 0.f;
        for (int i = tid; i < c; i += 1024) {
            const float x = 0.5f * Xr[i];
            const float d = fmaxf(x - tau, 0.f), q = d * d;
            S1 += q; SX = fmaf(q, x, SX); S3 = fmaf(q, d, S3);
        }
        S1 = wave_sum_f(S1); SX = wave_sum_f(SX); S3 = wave_sum_f(S3);
        __syncthreads();
        if (lane == 0) { s_r3[0][w] = S1; s_r3[1][w] = SX; s_r3[2][w] = S3; }
        __syncthreads();
        if (tid == 0) {
            float a = 0.f, bb = 0.f, g = 0.f;
            #pragma unroll
            for (int u = 0; u < NW; ++u) { a += s_r3[0][u]; bb += s_r3[1][u]; g += s_r3[2][u]; }
            const float omega = (1.f - g / (a * sqrtf(a))) * (4.f / 3.f);
            row_loss[r] = omega + 2.f * bb / a - s_xtg;
        }
    }
}

// ---------------------------------------------------------------------------
// general fallback kernel (c%4!=0 or c>32768): wave-per-row full scan
// ---------------------------------------------------------------------------
__global__ __launch_bounds__(256, 4)
void fallback_kernel(const float* __restrict__ X, const int* __restrict__ target,
                     float* __restrict__ row_loss, int n, int c) {
    const int wv   = threadIdx.x >> 6;
    const int lane = threadIdx.x & 63;
    const int r = blockIdx.x * 4 + wv;
    if (r >= n) return;
    const float* __restrict__ Xr = X + (size_t)r * (size_t)c;
    float m = -3e38f;
    for (int i = lane; i < c; i += 64) m = fmaxf(m, Xr[i]);
    m = wave_max_f(m);
    float lo = 0.5f * m - 1.0f, hi = 0.5f * m;
    for (int it = 0; it < NITER; ++it) {
        const float w4 = (hi - lo) * 0.25f;
        const float t1 = lo + w4, t2 = lo + 2.f * w4, t3 = lo + 3.f * w4;
        float f1 = 0.f, f2 = 0.f, f3 = 0.f;
        for (int i = lane; i < c; i += 64) {
            const float x = 0.5f * Xr[i];
            float d;
            d = fmaxf(x - t1, 0.f); f1 = fmaf(d, d, f1);
            d = fmaxf(x - t2, 0.f); f2 = fmaf(d, d, f2);
            d = fmaxf(x - t3, 0.f); f3 = fmaf(d, d, f3);
        }
        f1 = wave_sum_f(f1); f2 = wave_sum_f(f2); f3 = wave_sum_f(f3);
        const int cc = (f1 >= 1.f) + (f2 >= 1.f) + (f3 >= 1.f);
        lo += w4 * (float)cc;
        hi = lo + w4;
    }
    const float tau = 0.5f * (lo + hi);
    float S1 = 0.f, SX = 0.f, S3 = 0.f;
    for (int i = lane; i < c; i += 64) {
        const float x = 0.5f * Xr[i];
        const float d = fmaxf(x - tau, 0.f), q = d * d;
        S1 += q; SX = fmaf(q, x, SX); S3 = fmaf(q, d, S3);
    }
    S1 = wave_sum_f(S1); SX = wave_sum_f(SX); S3 = wave_sum_f(S3);
    if (lane == 0) {
        const float omega = (1.f - S3 / (S1 * sqrtf(S1))) * (4.f / 3.f);
        row_loss[r] = omega + 2.f * SX / S1 - Xr[target[r]];
    }
}

// ---------------------------------------------------------------------------
__global__ __launch_bounds__(1024)
void reduce_mean_kernel(const float* __restrict__ vv, float* __restrict__ out, int n) {
    __shared__ float s_red[16];
    float s = 0.f;
    for (int i = threadIdx.x; i < n; i += 1024) s += vv[i];
    s = wave_sum_f(s);
    const int wv = threadIdx.x >> 6;
    const int lane = threadIdx.x & 63;
    if (lane == 0) s_red[wv] = s;
    __syncthreads();
    if (threadIdx.x == 0) {
        float t = 0.f;
        for (int i = 0; i < 16; ++i) t += s_red[i];
        out[0] = t / (float)n;
    }
}

extern "C" void kernel_launch(void* const* d_in, const int* in_sizes, int n_in,
                              void* d_out, int out_size, void* d_ws, size_t ws_size,
                              hipStream_t stream) {
    (void)n_in; (void)out_size;
    const float* X      = (const float*)d_in[0];
    const int*   target = (const int*)d_in[1];
    float*       out    = (float*)d_out;
    float*       row_loss = (float*)d_ws;

    const int n = in_sizes[1];
    const int c = in_sizes[0] / n;

    const bool fast = ((c & 3) == 0) && (c <= 32768) &&
                      (ws_size >= (size_t)n * sizeof(float));
    if (fast) {
        entmax_loss_kernel<<<n, 1024, 0, stream>>>(X, target, row_loss, c);
    } else {
        fallback_kernel<<<(n + 3) / 4, 256, 0, stream>>>(X, target, row_loss, n, c);
    }
    reduce_mean_kernel<<<1, 1024, 0, stream>>>(row_loss, out, n);
}